// Round 7
// baseline (225.413 us; speedup 1.0000x reference)
//
#include <hip/hip_runtime.h>

// ============================================================================
// ContDecoder on MI355X — bf16 MFMA, round 9.
// MPTS=32, 1024 threads (16 waves), 55.8 KB dynamic LDS, 2 blocks/CU.
//
// Cycle model (r8 counters): ds_read traffic 972KB/blk x16 blk/CU ~ 186K cyc
// + 70K conflict cyc vs 348K total -> LDS-port-dominated. Schedule-forcing
// (ring/UPW/SGB) all flattened by compiler (VGPR pinned 28). Round-9 cuts
// LDS A-traffic STRUCTURALLY at constant 16-wave TLP via k-splitting:
//   - L1 (63% of LDS reads): wave w -> (q=w&7, khalf=w>>3); wave handles
//     n-tiles {q, q+8} over HALF the k-steps, A-frags shared across its 2
//     n-tiles: A-traffic 608->312 KB. Partial f32 accs reduced via LDS
//     scratch carved from the DEAD hA input region (barrier-separated).
//   - L2: same split (nt=q, halves of 10 steps): traffic equal but TLP 8->16
//     and latency-chain depth halved; scratch in dead hA bytes [640,1152).
//   - L0/L3..L6: r8 mapping unchanged.
// Kept (verified): swapped operands mfma(W,X) -> D[n,pt]; ds_write_b64
// epilogue + float4 bias. SGB directives removed (null, r8).
//
// LDS row layout per point (bf16): [xin 0..64 | hA 64..608 | hB 608..864],
// stride 872 elems (1744 B). Scratch (f32 partials) placement per layer:
//   L1: bytes [128,1152) of each row (= hA, dead after L1's MFMA reads;
//       BAR1 separates last read from first scratch write)
//   L2: bytes [640,1152) (no overlap with L2 input hB/xin, nor its output
//       hA elems 64..192 = bytes [128,384) -> no pre-barrier needed)
// L3 reads exactly hA elems 64..192 (L2 output) — scratch never aliases it.
// ============================================================================

#define NTH     1024
#define NWAVES  16
#define MPTS    32              // points per block (2 m-tiles of 16)
#define MTILES  (MPTS / 16)
#define SROW    872             // LDS row stride in bf16 elems
#define SROWB   (SROW * 2)      // 1744 bytes
#define XIN_OFF 0
#define HA_OFF  64
#define HB_OFF  608
#define NPOINTS (8 * 16384)
#define GRIDX   (NPOINTS / MPTS)   // 4096 blocks
#define LDSBYTES (MPTS * SROW * 2) // 55808 -> 2 blocks/CU

typedef short          short8  __attribute__((ext_vector_type(8)));
typedef short          short4v __attribute__((ext_vector_type(4)));
typedef float          f32x4   __attribute__((ext_vector_type(4)));
typedef unsigned short u16;

__device__ __forceinline__ u16 f2bf(float f) {
    unsigned int u = __builtin_bit_cast(unsigned int, f);
    u += 0x7fffu + ((u >> 16) & 1u);        // round-to-nearest-even
    return (u16)(u >> 16);
}

// ---------------------------------------------------------------------------
// Packed-weight geometry (16B fragments of 8 bf16). frag (l, nt, s, lane)
// holds B[s*32 + (lane>>4)*8 + j][nt*16 + (lane&15)], j=0..7, zero-padded.
// Identical byte layout as A- or B-operand of mfma_16x16x32 (HW-verified:
// swapped-operand kernels r6/r7/r8 passed with same absmax). UNCHANGED.
//   l : KHpad KSteps Ntiles  frag_base
//   0 :    0    2     33        0
//   1 :  544   19     16     4224
//   2 :  256   10      8    23680
//   3 :  128    6      4    28800
//   4 :   64    4      2    30336
//   5 :   32    3      1    30848
//   6 :   32    1      1    31040   total 31104 frags = 497664 B in d_ws
// ---------------------------------------------------------------------------
__constant__ int pk_base8[8] = {0, 4224, 23680, 28800, 30336, 30848, 31040, 31104};
__constant__ int pk_ks[7]    = {2, 19, 10, 6, 4, 3, 1};
__constant__ int pk_khp[7]   = {0, 544, 256, 128, 64, 32, 32};
__constant__ int pk_kact[7]  = {0, 516, 256, 128, 64, 32, 16};
__constant__ int pk_nact[7]  = {516, 256, 128, 64, 32, 16, 2};

struct WPtrs { const float* W[7]; };

__global__ void pack_weights(WPtrs wp, u16* __restrict__ out)
{
    const int f = blockIdx.x * blockDim.x + threadIdx.x;
    if (f >= 31104) return;
    int l = 0;
    while (l < 6 && f >= pk_base8[l + 1]) ++l;
    const int r    = f - pk_base8[l];
    const int lane = r & 63;
    const int t    = r >> 6;
    const int ks   = pk_ks[l];
    const int s    = t % ks;
    const int nt   = t / ks;
    const int n    = nt * 16 + (lane & 15);
    const int k0   = s * 32 + (lane >> 4) * 8;
    const int nact = pk_nact[l];
    const int khp  = pk_khp[l];
    const int kact = pk_kact[l];
    const float* W = wp.W[l];

    union { short8 v; u16 e[8]; } frag;
#pragma unroll
    for (int j = 0; j < 8; ++j) {
        const int k = k0 + j;
        float v = 0.0f;
        if (n < nact) {
            if (k < khp) {
                if (k < kact) v = W[k * nact + n];
            } else {
                const int xr = k - khp;
                if (xr < 37) v = W[(kact + xr) * nact + n];
            }
        }
        frag.e[j] = f2bf(v);
    }
    *(short8*)(out + (size_t)f * 8) = frag.v;
}

// ---------------------------------------------------------------------------
// One MLP layer.
// KSPLIT=1: r8 mapping — wave w handles n-tiles {w, w+16, ...} < NT, both
//   m-tiles. Per K-step: 2 ds_read (A) + 1 global load (B) + 2 MFMA.
// KSPLIT=2: wave w -> (q=w&7, khalf=w>>3); n-tiles {q, q+8, ...} < NT over
//   k-steps [0,SMID) or [SMID,KS). A-frags shared across the wave's n-tiles.
//   khalf1 writes f32 partials to scratch (SCRB byte offset in each point
//   row); barrier; khalf0 adds partner partials and runs the epilogue.
//   BAR1: extra pre-write barrier when scratch aliases the layer's input.
// Swapped operands: D[n,pt]: col pt = lane&15, row n = (lane>>4)*4 + r.
// ---------------------------------------------------------------------------
template<int KHP, int HSEG, int OSEG, int NT, int NACT, int LBASE,
         int KSPLIT, int SCRB, bool BAR1, bool XIN, bool RELU, bool GOUT>
__device__ __forceinline__ void mlayer(const u16* __restrict__ wpack,
                                       const float* __restrict__ bias,
                                       u16* __restrict__ s_act,
                                       float* __restrict__ gout, int p0,
                                       int wave, int lane)
{
    constexpr int KHS = KHP / 32;
    constexpr int KS  = KHS + (XIN ? 2 : 0);
    constexpr int MS  = MTILES;        // 2 m-tiles, both owned by each wave
    const int lm = lane & 15;
    const int lq = lane >> 4;
    const u16* wl = wpack + LBASE + lane * 8;

    const u16* arow[MS];
#pragma unroll
    for (int m = 0; m < MS; ++m)
        arow[m] = s_act + (m * 16 + lm) * SROW + lq * 8;

    if constexpr (KSPLIT == 1) {
        for (int nt = wave; nt < NT; nt += NWAVES) {
            const u16* bp = wl + (size_t)nt * KS * 512;

            f32x4 acc[MS];
#pragma unroll
            for (int m = 0; m < MS; ++m)
                acc[m] = (f32x4){0.f, 0.f, 0.f, 0.f};

#pragma unroll
            for (int s = 0; s < KS; ++s) {
                const int ab = (s < KHS) ? (HSEG + s * 32)
                                         : (XIN_OFF + (s - KHS) * 32);
                short8 a[MS];
#pragma unroll
                for (int m = 0; m < MS; ++m)
                    a[m] = *(const short8*)(arow[m] + ab);
                const short8 b = *(const short8*)(bp + (size_t)s * 512);
#pragma unroll
                for (int m = 0; m < MS; ++m)
                    acc[m] = __builtin_amdgcn_mfma_f32_16x16x32_bf16(b, a[m], acc[m], 0, 0, 0);
            }

            const int bn = nt * 16 + lq * 4;
            float bv[4];
            if (bn + 4 <= NACT) {
                const f32x4 b4 = *(const f32x4*)(bias + bn);
                bv[0] = b4[0]; bv[1] = b4[1]; bv[2] = b4[2]; bv[3] = b4[3];
            } else {
#pragma unroll
                for (int r = 0; r < 4; ++r)
                    bv[r] = (bn + r < NACT) ? bias[bn + r] : 0.f;
            }
            if (GOUT) {
                if (lq == 0) {             // only n=0,1 valid (NACT=2)
#pragma unroll
                    for (int m = 0; m < MS; ++m) {
                        float2 o;
                        o.x = acc[m][0] + bv[0];
                        o.y = acc[m][1] + bv[1];
                        *(float2*)(gout + (size_t)(p0 + m * 16 + lm) * 2) = o;
                    }
                }
            } else {
#pragma unroll
                for (int m = 0; m < MS; ++m) {
                    short4v o;
#pragma unroll
                    for (int r = 0; r < 4; ++r) {
                        float v = acc[m][r] + bv[r];
                        if (RELU) v = fmaxf(v, 0.f);
                        o[r] = (short)f2bf(v);
                    }
                    *(short4v*)(s_act + (size_t)(m * 16 + lm) * SROW + OSEG + bn) = o;
                }
            }
        }
    } else {
        // ---------------- KSPLIT == 2 ----------------
        constexpr int NTN  = NT / 8;       // L1: 2, L2: 1
        constexpr int SMID = (KS + 1) / 2; // L1: 10/9, L2: 5/5
        const int q  = wave & 7;
        const int kh = wave >> 3;          // wave-uniform

        const u16* bp[NTN];
#pragma unroll
        for (int i = 0; i < NTN; ++i)
            bp[i] = wl + (size_t)(q + 8 * i) * KS * 512;

        f32x4 acc[NTN][MS];
#pragma unroll
        for (int i = 0; i < NTN; ++i)
#pragma unroll
            for (int m = 0; m < MS; ++m)
                acc[i][m] = (f32x4){0.f, 0.f, 0.f, 0.f};

#define KSTEP(s_) { \
            const int ab = ((s_) < KHS) ? (HSEG + (s_) * 32) \
                                        : (XIN_OFF + ((s_) - KHS) * 32); \
            short8 a[MS]; \
            for (int m = 0; m < MS; ++m) \
                a[m] = *(const short8*)(arow[m] + ab); \
            for (int i = 0; i < NTN; ++i) { \
                const short8 b = *(const short8*)(bp[i] + (size_t)(s_) * 512); \
                for (int m = 0; m < MS; ++m) \
                    acc[i][m] = __builtin_amdgcn_mfma_f32_16x16x32_bf16(b, a[m], acc[i][m], 0, 0, 0); \
            } }

        if (kh == 0) {
#pragma unroll
            for (int s = 0; s < SMID; ++s) KSTEP(s)
        } else {
#pragma unroll
            for (int s = SMID; s < KS; ++s) KSTEP(s)
        }
#undef KSTEP

        if constexpr (BAR1) __syncthreads();   // input reads done before
                                               // scratch overwrites input
        if (kh == 1) {                         // write f32 partials
#pragma unroll
            for (int i = 0; i < NTN; ++i) {
                const int nt = q + 8 * i;
#pragma unroll
                for (int m = 0; m < MS; ++m) {
                    char* sp = (char*)s_act + (size_t)(m * 16 + lm) * SROWB
                             + SCRB + nt * 64 + lq * 16;
                    *(f32x4*)sp = acc[i][m];
                }
            }
        }
        __syncthreads();                       // partials visible
        if (kh == 0) {                         // reduce + epilogue
#pragma unroll
            for (int i = 0; i < NTN; ++i) {
                const int nt = q + 8 * i;
#pragma unroll
                for (int m = 0; m < MS; ++m) {
                    const char* sp = (const char*)s_act
                                   + (size_t)(m * 16 + lm) * SROWB
                                   + SCRB + nt * 64 + lq * 16;
                    acc[i][m] += *(const f32x4*)sp;
                }

                const int bn = nt * 16 + lq * 4;
                float bv[4];
                if (bn + 4 <= NACT) {
                    const f32x4 b4 = *(const f32x4*)(bias + bn);
                    bv[0] = b4[0]; bv[1] = b4[1]; bv[2] = b4[2]; bv[3] = b4[3];
                } else {
#pragma unroll
                    for (int r = 0; r < 4; ++r)
                        bv[r] = (bn + r < NACT) ? bias[bn + r] : 0.f;
                }
#pragma unroll
                for (int m = 0; m < MS; ++m) {
                    short4v o;
#pragma unroll
                    for (int r = 0; r < 4; ++r) {
                        float v = acc[i][m][r] + bv[r];
                        if (RELU) v = fmaxf(v, 0.f);
                        o[r] = (short)f2bf(v);
                    }
                    *(short4v*)(s_act + (size_t)(m * 16 + lm) * SROW + OSEG + bn) = o;
                }
            }
        }
    }
}

struct MainParams {
    const float* lr;     // [B,2,64,64]
    const float* ctx;    // [B,32,64,64]
    const float* eps;    // [B,64,64]
    const float* coord;  // [B,N,2]
    const float* Bb[7];  // biases (fp32)
    const u16*   wpack;  // packed bf16 weights in d_ws
    float*       out;    // [B,N,2]
};

__global__ __launch_bounds__(NTH, 8)   // 8 waves/EU = 32 waves/CU = 2 blocks
void cont_decoder_mfma(MainParams p)
{
    extern __shared__ u16 s_act[];         // MPTS*SROW bf16 = 55808 B
    __shared__ int   s_x0[MPTS], s_y0[MPTS];
    __shared__ float s_wx[MPTS], s_wy[MPTS];

    const int tid  = threadIdx.x;
    const int wave = tid >> 6;
    const int lane = tid & 63;
    const int p0   = blockIdx.x * MPTS;
    const int b    = p0 >> 14;             // 16384 points per batch

    // ---- zero pad regions: xin[37..64) and hA[528..544) (cols 592..608) ----
    for (int i = tid; i < MPTS * 43; i += NTH) {
        const int pt = i / 43, c = i % 43;
        const int col = (c < 27) ? (37 + c) : (592 + (c - 27));
        s_act[pt * SROW + col] = 0;
    }

    // ---- bilinear params + coord features ----
    if (tid < MPTS) {
        const int pt = p0 + tid;
        const float cx = p.coord[2 * pt];
        const float cy = p.coord[2 * pt + 1];
        const float gx = (cx + 1.0f) * 32.0f - 0.5f;   // align_corners=False
        const float gy = (cy + 1.0f) * 32.0f - 0.5f;
        const float fx0 = floorf(gx), fy0 = floorf(gy);
        s_x0[tid] = (int)fx0;
        s_y0[tid] = (int)fy0;
        s_wx[tid] = gx - fx0;
        s_wy[tid] = gy - fy0;
        s_act[tid * SROW + 32] = f2bf(cx);
        s_act[tid * SROW + 33] = f2bf(cy);
    }
    __syncthreads();

    // ---- sample 35 channels/point (ref swaps spatial axes: val = g[b,c,x,y]) ----
    for (int idx = tid; idx < MPTS * 35; idx += NTH) {
        const int t = idx / 35;
        const int c = idx % 35;
        const float* base;
        int col;
        if (c < 32)      { base = p.ctx + (size_t)(b * 32 + c) * 4096;       col = c; }
        else if (c < 34) { base = p.lr  + (size_t)(b * 2 + (c - 32)) * 4096; col = 34 + (c - 32); }
        else             { base = p.eps + (size_t)b * 4096;                   col = 36; }

        const int   x0 = s_x0[t], y0 = s_y0[t];
        const float wx = s_wx[t], wy = s_wy[t];
        const int x1 = x0 + 1, y1 = y0 + 1;
        const bool xv0 = (x0 >= 0) & (x0 < 64);
        const bool xv1 = (x1 >= 0) & (x1 < 64);
        const bool yv0 = (y0 >= 0) & (y0 < 64);
        const bool yv1 = (y1 >= 0) & (y1 < 64);
        const int xc0 = min(max(x0, 0), 63), xc1 = min(max(x1, 0), 63);
        const int yc0 = min(max(y0, 0), 63), yc1 = min(max(y1, 0), 63);

        const float w00 = (1.0f - wx) * (1.0f - wy) * ((xv0 && yv0) ? 1.0f : 0.0f);
        const float w10 = wx * (1.0f - wy)          * ((xv1 && yv0) ? 1.0f : 0.0f);
        const float w01 = (1.0f - wx) * wy          * ((xv0 && yv1) ? 1.0f : 0.0f);
        const float w11 = wx * wy                   * ((xv1 && yv1) ? 1.0f : 0.0f);

        const float val = w00 * base[xc0 * 64 + yc0]
                        + w10 * base[xc1 * 64 + yc0]
                        + w01 * base[xc0 * 64 + yc1]
                        + w11 * base[xc1 * 64 + yc1];
        s_act[t * SROW + col] = f2bf(val);
    }
    __syncthreads();

    // ---- MLP:  xin(37p64) ->W0-> hA(516p528) ->W1-> hB(256) ->W2-> hA(128)
    //            ->W3-> hB(64) ->W4-> hA(32) ->W5-> hB(16) ->W6-> out(2)
    //  L1/L2 use KSPLIT=2 (k-halved waves + LDS partial reduce).
    //       KHP  HSEG    OSEG    NT  NACT LBASE  KSP SCRB  BAR1   XIN   RELU   GOUT
    mlayer<  0,  HA_OFF, HA_OFF, 33, 516, 0,      1,  0,    false, true,  true,  false>(p.wpack, p.Bb[0], s_act, nullptr, p0, wave, lane);
    __syncthreads();
    mlayer<544,  HA_OFF, HB_OFF, 16, 256, 33792,  2,  128,  true,  true,  true,  false>(p.wpack, p.Bb[1], s_act, nullptr, p0, wave, lane);
    __syncthreads();
    mlayer<256,  HB_OFF, HA_OFF,  8, 128, 189440, 2,  640,  false, true,  true,  false>(p.wpack, p.Bb[2], s_act, nullptr, p0, wave, lane);
    __syncthreads();
    mlayer<128,  HA_OFF, HB_OFF,  4,  64, 230400, 1,  0,    false, true,  true,  false>(p.wpack, p.Bb[3], s_act, nullptr, p0, wave, lane);
    __syncthreads();
    mlayer< 64,  HB_OFF, HA_OFF,  2,  32, 242688, 1,  0,    false, true,  true,  false>(p.wpack, p.Bb[4], s_act, nullptr, p0, wave, lane);
    __syncthreads();
    mlayer< 32,  HA_OFF, HB_OFF,  1,  16, 246784, 1,  0,    false, true,  true,  false>(p.wpack, p.Bb[5], s_act, nullptr, p0, wave, lane);
    __syncthreads();
    mlayer< 32,  HB_OFF, 0,       1,   2, 248320, 1,  0,    false, false, false, true >(p.wpack, p.Bb[6], s_act, p.out,   p0, wave, lane);
}

extern "C" void kernel_launch(void* const* d_in, const int* in_sizes, int n_in,
                              void* d_out, int out_size, void* d_ws, size_t ws_size,
                              hipStream_t stream)
{
    WPtrs wp;
    for (int l = 0; l < 7; ++l) wp.W[l] = (const float*)d_in[4 + 2 * l];

    MainParams p;
    p.lr    = (const float*)d_in[0];
    p.ctx   = (const float*)d_in[1];
    p.eps   = (const float*)d_in[2];
    p.coord = (const float*)d_in[3];
    for (int l = 0; l < 7; ++l) p.Bb[l] = (const float*)d_in[5 + 2 * l];
    p.wpack = (const u16*)d_ws;
    p.out   = (float*)d_out;

    // Opt in to large dynamic LDS (idempotent; not a stream op, capture-safe).
    hipFuncSetAttribute((const void*)cont_decoder_mfma,
                        hipFuncAttributeMaxDynamicSharedMemorySize, LDSBYTES);

    hipLaunchKernelGGL(pack_weights, dim3(122), dim3(256), 0, stream, wp, (u16*)d_ws);
    hipLaunchKernelGGL(cont_decoder_mfma, dim3(GRIDX), dim3(NTH), LDSBYTES, stream, p);
}